// Round 9
// baseline (694.506 us; speedup 1.0000x reference)
//
#include <hip/hip_runtime.h>

// ATTNRNNAgent: B=4096, N=64, E=128, A=32, nh=8, e=32, HID=256, ATT=256, N_ACT=32
// K0 -> 2x( k1_fqkv, k2_attn ) -> k3_gru -> k4_out
// k3: split-K wave-pairing. 8 waves = 4 rowgroups x 2 K-halves; wave = 32 rows (mt=2),
//     half-K A-panel (64 VGPR) + 12 ffrag acc (48) -> fits 128 VGPR, and B-reads per MFMA
//     are HALVED vs R8 (48 reads feed 96 MFMAs per jb). gi (att x wih, K 0..255) computed
//     fully by half0; gh (h0 x whh, K 256..511) by half1; r/z partials exchanged via a
//     conflict-free [4][48][64] f32 LDS buffer (identical D-layouts -> flat lane/reg swap).
// q is stored in-place in A2's att columns (k2 reads q, overwrites with att; same addresses,
//     dataflow-ordered within wave) -> no qC buffer -> 2 chunks instead of 4.

using bfrag = __attribute__((ext_vector_type(8))) short;   // 8 bf16
using ffrag = __attribute__((ext_vector_type(4))) float;   // 4 f32 acc

#define MFMA(a,b,c) __builtin_amdgcn_mfma_f32_16x16x32_bf16((a),(b),(c),0,0,0)
// XOR swizzle for row-major bf16 LDS tiles (16B granular)
#define SWZ(row,col,S,xm) ((row)*(S) + ((((col)&~7) ^ (((row)&(xm))<<3)) | ((col)&7)))

// ws layout (in shorts). A2 first (131072 x 512), then bf16 weights, then flag.
#define OFF_A2   0L
#define OFF_FC1  67108864L
#define OFF_QW   67141632L
#define OFF_KW   67207168L
#define OFF_VW   67272704L
#define OFF_WIH  67338240L
#define OFF_WHH  67534848L
#define OFF_OW   67731456L
#define OFF_FLAG 67739648L
#define WS_NEED_BYTES 135479552L

__device__ inline unsigned short f2bf(float x){
  union { float f; unsigned u; } v; v.f = x;
  unsigned r = v.u + 0x7fffu + ((v.u >> 16) & 1u);   // RNE
  return (unsigned short)(r >> 16);
}
__device__ inline float bf2f(short b){
  union { unsigned u; float f; } v; v.u = ((unsigned)(unsigned short)b) << 16;
  return v.f;
}
__device__ inline bool getmask(const void* p, long i, int byteflag){
  return byteflag ? (((const unsigned char*)p)[i] != 0)
                  : (((const int*)p)[i] != 0);
}
__device__ inline ffrag fzero(){ ffrag z; z[0]=0.f; z[1]=0.f; z[2]=0.f; z[3]=0.f; return z; }

// ---------------- K0: weights -> bf16, A2 h0-half, detect mask dtype ----------------
__global__ void k0_prep(const float* __restrict__ fc1, const float* __restrict__ qw,
    const float* __restrict__ kw, const float* __restrict__ vw, const float* __restrict__ wih,
    const float* __restrict__ whh, const float* __restrict__ ow, const float* __restrict__ h0,
    const void* __restrict__ obsm, short* __restrict__ ws){
  long tid = (long)blockIdx.x*blockDim.x + threadIdx.x;
  long n = (long)gridDim.x*blockDim.x;
  if (tid == 0){
    const int* mi = (const int*)obsm;
    int f = 0;
    for (int i=0;i<256;i++){ if ((unsigned)mi[i] > 1u){ f = 1; break; } }
    ((int*)(ws + OFF_FLAG))[0] = f;
  }
  for (long i=tid; i<32768; i+=n) ws[OFF_FC1+i] = (short)f2bf(fc1[i]);
  for (long i=tid; i<65536; i+=n){
    ws[OFF_QW+i] = (short)f2bf(qw[i]);
    ws[OFF_KW+i] = (short)f2bf(kw[i]);
    ws[OFF_VW+i] = (short)f2bf(vw[i]);
  }
  for (long i=tid; i<196608; i+=n){
    ws[OFF_WIH+i] = (short)f2bf(wih[i]);
    ws[OFF_WHH+i] = (short)f2bf(whh[i]);
  }
  for (long i=tid; i<8192; i+=n) ws[OFF_OW+i] = (short)f2bf(ow[i]);
  // A2 h0 half (2 floats -> 1 packed uint): A2[row*512+256+2j..+1] = bf16(h0[row*256+2j..])
  const float2* h2 = (const float2*)h0;
  unsigned* a2u = (unsigned*)(ws + OFF_A2);
  for (long i=tid; i<16777216L; i+=n){
    long row = i >> 7; int j = (int)(i & 127);
    float2 v = h2[i];
    unsigned pk = (unsigned)f2bf(v.x) | ((unsigned)f2bf(v.y) << 16);
    a2u[row*256 + 128 + j] = pk;
  }
}

// ---------------- K1: fused fc1 + QKV projection (per 131072-row chunk) ----------------
__global__ __launch_bounds__(512) void k1_fqkv(const float* __restrict__ inp,
    const short* __restrict__ fc1B, const float* __restrict__ fc1_b,
    const short* __restrict__ wq, const short* __restrict__ wk, const short* __restrict__ wv,
    const float* __restrict__ qb, const float* __restrict__ kb, const float* __restrict__ vb,
    short* __restrict__ A2, short* __restrict__ kC, short* __restrict__ vC, int chunkB){
  __shared__ __align__(16) short smem[65536];   // 128 KB
  short* a_s  = smem;            // phase1 A: 128x128 (32 KB)
  short* fw_s = smem + 16384;    // phase1 W: 256x128 (64 KB)
  short* x_s  = smem;            // phase2 X: 128x256 (64 KB)
  int t = threadIdx.x;
  long R0 = (long)blockIdx.x * 128;            // chunk-local row base
  long grow0 = (long)chunkB*131072 + R0;       // global input row base
  int lane = t&63, w = t>>6, lr = lane&15, ko = lane>>4;
  for (int i=0;i<4;i++){
    int c = t + i*512; int row = c>>4; int cc = (c&15)*8;
    const float* src = inp + (grow0 + row)*128 + cc;
    float4 f0 = *(const float4*)src; float4 f1 = *(const float4*)(src+4);
    bfrag v8;
    v8[0]=(short)f2bf(f0.x); v8[1]=(short)f2bf(f0.y); v8[2]=(short)f2bf(f0.z); v8[3]=(short)f2bf(f0.w);
    v8[4]=(short)f2bf(f1.x); v8[5]=(short)f2bf(f1.y); v8[6]=(short)f2bf(f1.z); v8[7]=(short)f2bf(f1.w);
    *(bfrag*)(a_s + SWZ(row, cc, 128, 7)) = v8;
  }
  for (int i=0;i<8;i++){
    int c = t + i*512; int row = c>>4; int cc = (c&15)*8;
    *(bfrag*)(fw_s + SWZ(row, cc, 128, 7)) = *(const bfrag*)(fc1B + row*128 + cc);
  }
  __syncthreads();
  ffrag acc1[16];
  #pragma unroll
  for (int i=0;i<16;i++) acc1[i]=fzero();
  for (int ks=0; ks<4; ks++){
    int kc = ks*32 + ko*8;
    bfrag a = *(const bfrag*)(a_s + SWZ(w*16+lr, kc, 128, 7));
    #pragma unroll
    for (int nt=0; nt<16; nt++){
      bfrag bb = *(const bfrag*)(fw_s + SWZ(nt*16+lr, kc, 128, 7));
      acc1[nt] = MFMA(a, bb, acc1[nt]);
    }
  }
  __syncthreads();   // all phase1 LDS reads complete -> reuse smem
  #pragma unroll
  for (int nt=0; nt<16; nt++){
    float bias = fc1_b[nt*16+lr];
    #pragma unroll
    for (int r=0;r<4;r++){
      int row = w*16 + ko*4 + r;
      float v = acc1[nt][r] + bias; v = v>0.f?v:0.f;
      x_s[SWZ(row, nt*16+lr, 256, 7)] = (short)f2bf(v);
    }
  }
  bfrag a_r[8];
  #pragma unroll
  for (int ks=0; ks<8; ks++)
    a_r[ks] = *(const bfrag*)(x_s + SWZ(w*16+lr, ks*32+ko*8, 256, 7));
  auto STAGE2 = [&](int s){
    int kind = s>>2; int rb = (s&3)*64;
    const short* wsrc = (kind==0?wq:(kind==1?wk:wv)) + (long)rb*256;
    short* dst = smem + 32768 + (s&1)*16384;
    #pragma unroll
    for (int i=0;i<4;i++){
      int c = t + i*512; int row = c>>5; int cc = (c&31)*8;
      *(bfrag*)(dst + SWZ(row, cc, 256, 7)) = *(const bfrag*)(wsrc + (long)row*256 + cc);
    }
  };
  STAGE2(0);
  __syncthreads();
  for (int s=0; s<12; s++){
    if (s < 11) STAGE2(s+1);
    const short* wcur = smem + 32768 + (s&1)*16384;
    ffrag acc2[4];
    #pragma unroll
    for (int i=0;i<4;i++) acc2[i]=fzero();
    #pragma unroll
    for (int ks=0; ks<8; ks++){
      int kc = ks*32 + ko*8;
      #pragma unroll
      for (int nt=0; nt<4; nt++){
        bfrag bb = *(const bfrag*)(wcur + SWZ(nt*16+lr, kc, 256, 7));
        acc2[nt] = MFMA(a_r[ks], bb, acc2[nt]);
      }
    }
    int kind = s>>2; int rb = (s&3)*64;
    const float* bsrc = (kind==0?qb:(kind==1?kb:vb));
    #pragma unroll
    for (int nt=0; nt<4; nt++){
      int colk = rb + nt*16 + lr;
      float bias = bsrc[colk];
      #pragma unroll
      for (int r=0;r<4;r++){
        int row = w*16 + ko*4 + r;
        long rl = R0 + row;
        float v = acc2[nt][r] + bias;
        if (kind==0){
          if ((row&32)==0){                       // q: only agent rows n<32
            long grow = grow0 + row;
            long qrow = ((grow>>6)<<5) + (grow&31);
            A2[qrow*512 + colk] = (short)f2bf(v);  // q in-place in A2 att cols
          }
        } else if (kind==1){
          kC[rl*256 + colk] = (short)f2bf(v);
        } else {
          v = v>0.f?v:0.f;
          vC[rl*256 + colk] = (short)f2bf(v);
        }
      }
    }
    __syncthreads();
  }
}

// ---------------- K2: attention, one wave per (b,head); q read from / att written to A2 ----
__global__ __launch_bounds__(512,4) void k2_attn(const short* __restrict__ kC,
    const short* __restrict__ vC, const void* __restrict__ obsm, short* __restrict__ A2,
    const int* __restrict__ flagp, int chunkB){
  __shared__ __align__(16) short vT_s[8][2048];   // per-wave v^T [e=32][n=64]
  __shared__ __align__(16) short p_s[8][2048];    // per-wave p   [a=32][n=64]
  __shared__ unsigned char m_s[2048];             // obs_mask rows 0..31
  int t = threadIdx.x, bl = blockIdx.x;
  long b = (long)chunkB*2048 + bl;
  int lane = t&63, w = t>>6, lr = lane&15, ko = lane>>4;
  int mflag = *flagp;
  if (mflag){
    uchar4 mv = *(const uchar4*)((const unsigned char*)obsm + b*4096 + t*4);
    m_s[t*4]=mv.x; m_s[t*4+1]=mv.y; m_s[t*4+2]=mv.z; m_s[t*4+3]=mv.w;
  } else {
    int4 mv = *(const int4*)((const int*)obsm + b*4096 + t*4);
    m_s[t*4]  =(unsigned char)(mv.x!=0); m_s[t*4+1]=(unsigned char)(mv.y!=0);
    m_s[t*4+2]=(unsigned char)(mv.z!=0); m_s[t*4+3]=(unsigned char)(mv.w!=0);
  }
  const int h = w;
  const short* qh = A2 + ((long)b*32)*512 + h*32 + ko*8;   // q stored at stride 512
  bfrag a_q[2];
  #pragma unroll
  for (int mt=0; mt<2; mt++) a_q[mt] = *(const bfrag*)(qh + (long)(mt*16+lr)*512);
  const short* kh = kC + ((long)bl*64)*256 + h*32 + ko*8;
  bfrag b_k[4];
  #pragma unroll
  for (int nt=0; nt<4; nt++) b_k[nt] = *(const bfrag*)(kh + (nt*16+lr)*256);
  #pragma unroll
  for (int i=0;i<4;i++){
    int n = i*16 + (lane>>2); int e0 = (lane&3)*8;
    bfrag vv = *(const bfrag*)(vC + ((long)bl*64 + n)*256 + h*32 + e0);
    #pragma unroll
    for (int j=0;j<8;j++) vT_s[w][SWZ(e0+j, n, 64, 7)] = vv[j];
  }
  ffrag sc[2][4];
  #pragma unroll
  for (int mt=0; mt<2; mt++)
    #pragma unroll
    for (int nt=0; nt<4; nt++) sc[mt][nt] = MFMA(a_q[mt], b_k[nt], fzero());
  __syncthreads();   // m_s ready (vT/p are wave-private)
  const float scale = 0.17677669529663687f;   // 1/sqrt(32)
  float rsi[2][4];
  #pragma unroll
  for (int mt=0; mt<2; mt++){
    #pragma unroll
    for (int r=0; r<4; r++){
      int arow = mt*16 + ko*4 + r;
      float sv[4]; int mk[4];
      #pragma unroll
      for (int nt=0; nt<4; nt++){
        mk[nt] = m_s[arow*64 + nt*16 + lr];
        sv[nt] = sc[mt][nt][r] * scale;
      }
      float mx = -3.0e38f;
      #pragma unroll
      for (int nt=0; nt<4; nt++) if (!mk[nt]) mx = fmaxf(mx, sv[nt]);
      for (int d=1; d<16; d<<=1) mx = fmaxf(mx, __shfl_xor(mx, d));
      float sum = 0.f;
      #pragma unroll
      for (int nt=0; nt<4; nt++){
        float p = mk[nt] ? 0.f : __expf(sv[nt]-mx);
        sv[nt] = p; sum += p;
      }
      for (int d=1; d<16; d<<=1) sum += __shfl_xor(sum, d);
      rsi[mt][r] = sum > 0.f ? 1.f/sum : 0.f;   // all-masked row -> 0
      #pragma unroll
      for (int nt=0; nt<4; nt++)
        p_s[w][SWZ(arow, nt*16+lr, 64, 7)] = (short)f2bf(sv[nt]);
    }
  }
  ffrag o[2][2];
  #pragma unroll
  for (int mt=0;mt<2;mt++)
    #pragma unroll
    for (int nt=0;nt<2;nt++) o[mt][nt]=fzero();
  #pragma unroll
  for (int kk=0; kk<2; kk++){
    int kc = kk*32 + ko*8;
    bfrag pa0 = *(const bfrag*)(p_s[w]  + SWZ(lr,    kc, 64, 7));
    bfrag pa1 = *(const bfrag*)(p_s[w]  + SWZ(16+lr, kc, 64, 7));
    bfrag bv0 = *(const bfrag*)(vT_s[w] + SWZ(lr,    kc, 64, 7));
    bfrag bv1 = *(const bfrag*)(vT_s[w] + SWZ(16+lr, kc, 64, 7));
    o[0][0]=MFMA(pa0,bv0,o[0][0]); o[0][1]=MFMA(pa0,bv1,o[0][1]);
    o[1][0]=MFMA(pa1,bv0,o[1][0]); o[1][1]=MFMA(pa1,bv1,o[1][1]);
  }
  #pragma unroll
  for (int mt=0; mt<2; mt++)
    #pragma unroll
    for (int nt=0; nt<2; nt++)
      #pragma unroll
      for (int r=0; r<4; r++){
        int a = mt*16 + ko*4 + r;
        A2[((long)b*32 + a)*512 + h*32 + nt*16 + lr] = (short)f2bf(o[mt][nt][r]*rsi[mt][r]);
      }
}

// ---------------- K3: GRU, split-K wave-pairing ----------------
// block = 128 rows, 8 waves = 4 rowgroups x 2 K-halves. wave = 32 rows (mt=2), half-K.
// half0: gi = att @ wih^T (complete). half1: gh = h0 @ whh^T (complete).
// r/z summed across halves via part_s; epilogue by half1. 2 barriers/jb.
__global__ __launch_bounds__(512) void k3_gru(const short* __restrict__ A2,
    const short* __restrict__ wihB, const short* __restrict__ whhB,
    const float* __restrict__ b_ih, const float* __restrict__ b_hh,
    const void* __restrict__ scen, float* __restrict__ hout, const int* __restrict__ flagp){
  __shared__ __align__(16) short w_s[49152];   // 6 slabs 32x256: [wih r,z,n | whh r,z,n] = 96 KB
  __shared__ float part_s[4][48][64];          // half0 partials per rowgroup, 48 KB
  int t = threadIdx.x, bid = blockIdx.x;
  long R0 = (long)bid * 128;
  int mflag = *flagp;
  int lane = t&63, w = t>>6, lr = lane&15, ko = lane>>4;
  int g = w & 3, half = w >> 2;
  long rowbase = R0 + (long)g*32;
  // A-panel: this wave's K-half of its 32 rows (2 mt x 8 ks = 64 VGPR), read ONCE
  const short* Ab = A2 + (rowbase + lr)*512 + half*256 + ko*8;
  bfrag A[2][8];
  #pragma unroll
  for (int mt=0; mt<2; mt++)
    #pragma unroll
    for (int ks=0; ks<8; ks++)
      A[mt][ks] = *(const bfrag*)(Ab + (long)mt*16*512 + ks*32);
  const short* wc = w_s + half*24576;   // half0 -> wih slabs, half1 -> whh slabs
  for (int jb=0; jb<8; jb++){
    // stage 6 slabs (rows jb*32..+31 of each gate of both matrices)
    #pragma unroll
    for (int i=0;i<12;i++){
      int c = t + i*512; int slab = c>>10; int cm = c&1023; int row = cm>>5; int cc = (cm&31)*8;
      const short* src = (slab<3)
        ? wihB + ((long)(slab*256 + jb*32 + row))*256 + cc
        : whhB + ((long)((slab-3)*256 + jb*32 + row))*256 + cc;
      *(bfrag*)(w_s + slab*8192 + SWZ(row, cc, 256, 7)) = *(const bfrag*)src;
    }
    __syncthreads();   // weights ready; prev jb's partial reads complete
    ffrag aR[2][2], aZ[2][2], aX[2][2];   // [nt][mt]; X = in_ (half0) or hn (half1)
    #pragma unroll
    for (int nt=0;nt<2;nt++)
      #pragma unroll
      for (int mt=0;mt<2;mt++){ aR[nt][mt]=fzero(); aZ[nt][mt]=fzero(); aX[nt][mt]=fzero(); }
    #pragma unroll
    for (int ks=0; ks<8; ks++){
      int kc = ks*32 + ko*8;
      #pragma unroll
      for (int nt=0; nt<2; nt++){
        bfrag bR = *(const bfrag*)(wc + 0*8192 + SWZ(nt*16+lr, kc, 256, 7));
        aR[nt][0] = MFMA(A[0][ks], bR, aR[nt][0]);
        aR[nt][1] = MFMA(A[1][ks], bR, aR[nt][1]);
        bfrag bZ = *(const bfrag*)(wc + 1*8192 + SWZ(nt*16+lr, kc, 256, 7));
        aZ[nt][0] = MFMA(A[0][ks], bZ, aZ[nt][0]);
        aZ[nt][1] = MFMA(A[1][ks], bZ, aZ[nt][1]);
        bfrag bX = *(const bfrag*)(wc + 2*8192 + SWZ(nt*16+lr, kc, 256, 7));
        aX[nt][0] = MFMA(A[0][ks], bX, aX[nt][0]);
        aX[nt][1] = MFMA(A[1][ks], bX, aX[nt][1]);
      }
    }
    if (half == 0){   // publish gi partials (flat (lane,reg) indexing; layouts identical)
      #pragma unroll
      for (int nt=0; nt<2; nt++)
        #pragma unroll
        for (int mt=0; mt<2; mt++)
          #pragma unroll
          for (int rr=0; rr<4; rr++){
            part_s[g][((0*2+nt)*2+mt)*4+rr][lane] = aR[nt][mt][rr];
            part_s[g][((2+nt)*2+mt)*4+rr][lane]   = aZ[nt][mt][rr];
            part_s[g][((4+nt)*2+mt)*4+rr][lane]   = aX[nt][mt][rr];
          }
    }
    __syncthreads();   // partials ready
    if (half == 1){   // gates + h for jb's 32 cols
      #pragma unroll
      for (int nt=0; nt<2; nt++){
        int j = jb*32 + nt*16 + lr;
        float bir = b_ih[j],     bhr = b_hh[j];
        float biz = b_ih[256+j], bhz = b_hh[256+j];
        float bin = b_ih[512+j], bhn = b_hh[512+j];
        #pragma unroll
        for (int mt=0; mt<2; mt++){
          #pragma unroll
          for (int rr=0; rr<4; rr++){
            float ir = part_s[g][((0*2+nt)*2+mt)*4+rr][lane];
            float iz = part_s[g][((2+nt)*2+mt)*4+rr][lane];
            float in_ = part_s[g][((4+nt)*2+mt)*4+rr][lane];
            float hr = aR[nt][mt][rr], hz = aZ[nt][mt][rr], hn = aX[nt][mt][rr];
            long row = rowbase + mt*16 + ko*4 + rr;
            float rg = 1.f/(1.f + __expf(-(ir + hr + bir + bhr)));
            float zg = 1.f/(1.f + __expf(-(iz + hz + biz + bhz)));
            float ag = in_ + bin + rg*(hn + bhn);
            float ng = 2.f/(1.f + __expf(-2.f*ag)) - 1.f;   // tanh
            float h0v = bf2f(A2[row*512 + 256 + j]);
            float hv = (1.f - zg)*ng + zg*h0v;
            if (getmask(scen, row, mflag)) hv = 0.f;
            hout[row*256 + j] = hv;
          }
        }
      }
    }
  }
}

// ---------------- K4: q_out = h @ out_w^T + out_b (masked) ----------------
__global__ __launch_bounds__(512) void k4_out(const float* __restrict__ hout,
    const short* __restrict__ ow, const float* __restrict__ out_b,
    const void* __restrict__ scen, float* __restrict__ qout, const int* __restrict__ flagp){
  __shared__ __align__(16) short ow_s[32*256];
  int t = threadIdx.x; long R0 = (long)blockIdx.x * 256;
  int mflag = *flagp;
  for (int i=0;i<2;i++){
    int c = t + i*512; int row = c >> 5; int cc = (c & 31)*8;
    *(bfrag*)(ow_s + SWZ(row, cc, 256, 7)) = *(const bfrag*)(ow + row*256 + cc);
  }
  __syncthreads();
  int lane = t&63, w = t>>6, lr = lane&15, ko = lane>>4;
  ffrag acc[2][2];
  #pragma unroll
  for (int a=0;a<2;a++) for (int bq=0;bq<2;bq++) acc[a][bq]=fzero();
  for (int ks=0; ks<8; ks++){
    int kc = ks*32 + ko*8;
    #pragma unroll
    for (int mi=0; mi<2; mi++){
      long row = R0 + (w*2+mi)*16 + lr;
      const float* hp = hout + row*256 + kc;
      float4 f0 = *(const float4*)hp; float4 f1 = *(const float4*)(hp+4);
      bfrag a;
      a[0]=(short)f2bf(f0.x); a[1]=(short)f2bf(f0.y); a[2]=(short)f2bf(f0.z); a[3]=(short)f2bf(f0.w);
      a[4]=(short)f2bf(f1.x); a[5]=(short)f2bf(f1.y); a[6]=(short)f2bf(f1.z); a[7]=(short)f2bf(f1.w);
      #pragma unroll
      for (int nt=0; nt<2; nt++){
        bfrag bb = *(const bfrag*)(ow_s + SWZ(nt*16+lr, kc, 256, 7));
        acc[mi][nt] = MFMA(a, bb, acc[mi][nt]);
      }
    }
  }
  #pragma unroll
  for (int mi=0;mi<2;mi++)
    #pragma unroll
    for (int nt=0;nt<2;nt++){
      int col = nt*16 + lr;
      float ob = out_b[col];
      #pragma unroll
      for (int r=0;r<4;r++){
        long row = R0 + (w*2+mi)*16 + ko*4 + r;
        float qv = acc[mi][nt][r] + ob;
        if (getmask(scen, row, mflag)) qv = 0.f;
        qout[row*32 + col] = qv;
      }
    }
}

extern "C" void kernel_launch(void* const* d_in, const int* in_sizes, int n_in,
                              void* d_out, int out_size, void* d_ws, size_t ws_size,
                              hipStream_t stream){
  const float* inputs = (const float*)d_in[0];
  const float* hidden = (const float*)d_in[1];
  const float* fc1_w  = (const float*)d_in[2];
  const float* fc1_b  = (const float*)d_in[3];
  const float* q_w    = (const float*)d_in[4];
  const float* q_b    = (const float*)d_in[5];
  const float* k_w    = (const float*)d_in[6];
  const float* k_b    = (const float*)d_in[7];
  const float* v_w    = (const float*)d_in[8];
  const float* v_b    = (const float*)d_in[9];
  const float* w_ih   = (const float*)d_in[10];
  const float* w_hh   = (const float*)d_in[11];
  const float* b_ih   = (const float*)d_in[12];
  const float* b_hh   = (const float*)d_in[13];
  const float* out_w  = (const float*)d_in[14];
  const float* out_b  = (const float*)d_in[15];
  const void* obsm    = d_in[16];
  const void* scen    = d_in[17];
  (void)in_sizes; (void)n_in; (void)out_size;
  if ((long)ws_size < WS_NEED_BYTES) return;
  short* ws = (short*)d_ws;
  const int* flagp = (const int*)(ws + OFF_FLAG);
  float* qout = (float*)d_out;
  float* hout = qout + 4194304;
  // per-chunk k/v scratch in the dead hout region (2048 batches/chunk):
  short* kCs = (short*)hout;             // 2048*64*256 shorts = 67 MB
  short* vCs = kCs + 33554432L;          // 67 MB
  short* A2  = ws + OFF_A2;

  hipLaunchKernelGGL(k0_prep, dim3(2048), dim3(256), 0, stream,
      fc1_w, q_w, k_w, v_w, w_ih, w_hh, out_w, hidden, obsm, ws);
  for (int c=0; c<2; c++){
    hipLaunchKernelGGL(k1_fqkv, dim3(1024), dim3(512), 0, stream,
        inputs, ws + OFF_FC1, fc1_b, ws + OFF_QW, ws + OFF_KW, ws + OFF_VW,
        q_b, k_b, v_b, A2, kCs, vCs, c);
    hipLaunchKernelGGL(k2_attn, dim3(2048), dim3(512), 0, stream,
        kCs, vCs, obsm, A2, flagp, c);
  }
  hipLaunchKernelGGL(k3_gru, dim3(1024), dim3(512), 0, stream,
      A2, ws + OFF_WIH, ws + OFF_WHH, b_ih, b_hh, scen, hout, flagp);
  hipLaunchKernelGGL(k4_out, dim3(512), dim3(512), 0, stream,
      hout, ws + OFF_OW, out_b, scen, qout, flagp);
}

// Round 10
// 612.776 us; speedup vs baseline: 1.1334x; 1.1334x over previous
//
#include <hip/hip_runtime.h>

// ATTNRNNAgent: B=4096, N=64, E=128, A=32, nh=8, e=32, HID=256, ATT=256, N_ACT=32
// K0 -> 2x( k1_fqkv, k2_attn ) -> k3_gru -> k4_out
// k3 = R8 structure (mt=1, jb-in-block, 2x48KB ping-pong) + global_load_lds staging.
//   Weights for k3 are stored PRE-SWIZZLED + jb-blocked by k0 (source-permutation ==
//   read-permutation, LDS dest linear — guide rule #21/m173). Removes all staging
//   ds_writes + VGPR round-trip; prefetch flies under MFMA, drained by barriers.
// q is stored in-place in A2's att columns (k2 reads q, overwrites with att).

using bfrag = __attribute__((ext_vector_type(8))) short;   // 8 bf16
using ffrag = __attribute__((ext_vector_type(4))) float;   // 4 f32 acc

#define MFMA(a,b,c) __builtin_amdgcn_mfma_f32_16x16x32_bf16((a),(b),(c),0,0,0)
// XOR swizzle for row-major bf16 LDS tiles (16B granular)
#define SWZ(row,col,S,xm) ((row)*(S) + ((((col)&~7) ^ (((row)&(xm))<<3)) | ((col)&7)))

// ws layout (in shorts). A2 first (131072 x 512), then bf16 weights, then flag.
#define OFF_A2   0L
#define OFF_FC1  67108864L
#define OFF_QW   67141632L
#define OFF_KW   67207168L
#define OFF_VW   67272704L
#define OFF_WIH  67338240L   // k3 wih: [jb][gate][32][256], pre-swizzled
#define OFF_WHH  67534848L   // k3 whh: same layout
#define OFF_OW   67731456L
#define OFF_FLAG 67739648L
#define WS_NEED_BYTES 135479552L

__device__ inline unsigned short f2bf(float x){
  union { float f; unsigned u; } v; v.f = x;
  unsigned r = v.u + 0x7fffu + ((v.u >> 16) & 1u);   // RNE
  return (unsigned short)(r >> 16);
}
__device__ inline float bf2f(short b){
  union { unsigned u; float f; } v; v.u = ((unsigned)(unsigned short)b) << 16;
  return v.f;
}
__device__ inline bool getmask(const void* p, long i, int byteflag){
  return byteflag ? (((const unsigned char*)p)[i] != 0)
                  : (((const int*)p)[i] != 0);
}
__device__ inline ffrag fzero(){ ffrag z; z[0]=0.f; z[1]=0.f; z[2]=0.f; z[3]=0.f; return z; }
// async global->LDS, 16B per lane; lds ptr must be wave-uniform (HW adds lane*16)
__device__ inline void gload16(const short* g, short* l){
  __builtin_amdgcn_global_load_lds((const __attribute__((address_space(1))) void*)g,
                                   (__attribute__((address_space(3))) void*)l, 16, 0, 0);
}

// ---------------- K0: weights -> bf16 (k3 weights pre-swizzled), A2 h0-half, mask dtype ----
__global__ void k0_prep(const float* __restrict__ fc1, const float* __restrict__ qw,
    const float* __restrict__ kw, const float* __restrict__ vw, const float* __restrict__ wih,
    const float* __restrict__ whh, const float* __restrict__ ow, const float* __restrict__ h0,
    const void* __restrict__ obsm, short* __restrict__ ws){
  long tid = (long)blockIdx.x*blockDim.x + threadIdx.x;
  long n = (long)gridDim.x*blockDim.x;
  if (tid == 0){
    const int* mi = (const int*)obsm;
    int f = 0;
    for (int i=0;i<256;i++){ if ((unsigned)mi[i] > 1u){ f = 1; break; } }
    ((int*)(ws + OFF_FLAG))[0] = f;
  }
  for (long i=tid; i<32768; i+=n) ws[OFF_FC1+i] = (short)f2bf(fc1[i]);
  for (long i=tid; i<65536; i+=n){
    ws[OFF_QW+i] = (short)f2bf(qw[i]);
    ws[OFF_KW+i] = (short)f2bf(kw[i]);
    ws[OFF_VW+i] = (short)f2bf(vw[i]);
  }
  // k3 weights: [jb][gate][row32][256], column index pre-swizzled so that a LINEAR
  // global_load_lds fill yields the SWZ layout the MFMA B-reads expect.
  for (long i=tid; i<196608; i+=n){
    int R = (int)(i >> 8), c = (int)(i & 255);
    int gate = R >> 8, grow = R & 255;
    int jb = grow >> 5, row = grow & 31;
    long dst = (long)((jb*3 + gate)*32 + row)*256 + (c ^ ((row&7)<<3));
    ws[OFF_WIH + dst] = (short)f2bf(wih[i]);
    ws[OFF_WHH + dst] = (short)f2bf(whh[i]);
  }
  for (long i=tid; i<8192; i+=n) ws[OFF_OW+i] = (short)f2bf(ow[i]);
  // A2 h0 half (2 floats -> 1 packed uint): A2[row*512+256+2j..+1] = bf16(h0[row*256+2j..])
  const float2* h2 = (const float2*)h0;
  unsigned* a2u = (unsigned*)(ws + OFF_A2);
  for (long i=tid; i<16777216L; i+=n){
    long row = i >> 7; int j = (int)(i & 127);
    float2 v = h2[i];
    unsigned pk = (unsigned)f2bf(v.x) | ((unsigned)f2bf(v.y) << 16);
    a2u[row*256 + 128 + j] = pk;
  }
}

// ---------------- K1: fused fc1 + QKV projection (per 131072-row chunk) ----------------
__global__ __launch_bounds__(512) void k1_fqkv(const float* __restrict__ inp,
    const short* __restrict__ fc1B, const float* __restrict__ fc1_b,
    const short* __restrict__ wq, const short* __restrict__ wk, const short* __restrict__ wv,
    const float* __restrict__ qb, const float* __restrict__ kb, const float* __restrict__ vb,
    short* __restrict__ A2, short* __restrict__ kC, short* __restrict__ vC, int chunkB){
  __shared__ __align__(16) short smem[65536];   // 128 KB
  short* a_s  = smem;            // phase1 A: 128x128 (32 KB)
  short* fw_s = smem + 16384;    // phase1 W: 256x128 (64 KB)
  short* x_s  = smem;            // phase2 X: 128x256 (64 KB)
  int t = threadIdx.x;
  long R0 = (long)blockIdx.x * 128;            // chunk-local row base
  long grow0 = (long)chunkB*131072 + R0;       // global input row base
  int lane = t&63, w = t>>6, lr = lane&15, ko = lane>>4;
  for (int i=0;i<4;i++){
    int c = t + i*512; int row = c>>4; int cc = (c&15)*8;
    const float* src = inp + (grow0 + row)*128 + cc;
    float4 f0 = *(const float4*)src; float4 f1 = *(const float4*)(src+4);
    bfrag v8;
    v8[0]=(short)f2bf(f0.x); v8[1]=(short)f2bf(f0.y); v8[2]=(short)f2bf(f0.z); v8[3]=(short)f2bf(f0.w);
    v8[4]=(short)f2bf(f1.x); v8[5]=(short)f2bf(f1.y); v8[6]=(short)f2bf(f1.z); v8[7]=(short)f2bf(f1.w);
    *(bfrag*)(a_s + SWZ(row, cc, 128, 7)) = v8;
  }
  for (int i=0;i<8;i++){
    int c = t + i*512; int row = c>>4; int cc = (c&15)*8;
    *(bfrag*)(fw_s + SWZ(row, cc, 128, 7)) = *(const bfrag*)(fc1B + row*128 + cc);
  }
  __syncthreads();
  ffrag acc1[16];
  #pragma unroll
  for (int i=0;i<16;i++) acc1[i]=fzero();
  for (int ks=0; ks<4; ks++){
    int kc = ks*32 + ko*8;
    bfrag a = *(const bfrag*)(a_s + SWZ(w*16+lr, kc, 128, 7));
    #pragma unroll
    for (int nt=0; nt<16; nt++){
      bfrag bb = *(const bfrag*)(fw_s + SWZ(nt*16+lr, kc, 128, 7));
      acc1[nt] = MFMA(a, bb, acc1[nt]);
    }
  }
  __syncthreads();   // all phase1 LDS reads complete -> reuse smem
  #pragma unroll
  for (int nt=0; nt<16; nt++){
    float bias = fc1_b[nt*16+lr];
    #pragma unroll
    for (int r=0;r<4;r++){
      int row = w*16 + ko*4 + r;
      float v = acc1[nt][r] + bias; v = v>0.f?v:0.f;
      x_s[SWZ(row, nt*16+lr, 256, 7)] = (short)f2bf(v);
    }
  }
  bfrag a_r[8];
  #pragma unroll
  for (int ks=0; ks<8; ks++)
    a_r[ks] = *(const bfrag*)(x_s + SWZ(w*16+lr, ks*32+ko*8, 256, 7));
  auto STAGE2 = [&](int s){
    int kind = s>>2; int rb = (s&3)*64;
    const short* wsrc = (kind==0?wq:(kind==1?wk:wv)) + (long)rb*256;
    short* dst = smem + 32768 + (s&1)*16384;
    #pragma unroll
    for (int i=0;i<4;i++){
      int c = t + i*512; int row = c>>5; int cc = (c&31)*8;
      *(bfrag*)(dst + SWZ(row, cc, 256, 7)) = *(const bfrag*)(wsrc + (long)row*256 + cc);
    }
  };
  STAGE2(0);
  __syncthreads();
  for (int s=0; s<12; s++){
    if (s < 11) STAGE2(s+1);
    const short* wcur = smem + 32768 + (s&1)*16384;
    ffrag acc2[4];
    #pragma unroll
    for (int i=0;i<4;i++) acc2[i]=fzero();
    #pragma unroll
    for (int ks=0; ks<8; ks++){
      int kc = ks*32 + ko*8;
      #pragma unroll
      for (int nt=0; nt<4; nt++){
        bfrag bb = *(const bfrag*)(wcur + SWZ(nt*16+lr, kc, 256, 7));
        acc2[nt] = MFMA(a_r[ks], bb, acc2[nt]);
      }
    }
    int kind = s>>2; int rb = (s&3)*64;
    const float* bsrc = (kind==0?qb:(kind==1?kb:vb));
    #pragma unroll
    for (int nt=0; nt<4; nt++){
      int colk = rb + nt*16 + lr;
      float bias = bsrc[colk];
      #pragma unroll
      for (int r=0;r<4;r++){
        int row = w*16 + ko*4 + r;
        long rl = R0 + row;
        float v = acc2[nt][r] + bias;
        if (kind==0){
          if ((row&32)==0){                       // q: only agent rows n<32
            long grow = grow0 + row;
            long qrow = ((grow>>6)<<5) + (grow&31);
            A2[qrow*512 + colk] = (short)f2bf(v);  // q in-place in A2 att cols
          }
        } else if (kind==1){
          kC[rl*256 + colk] = (short)f2bf(v);
        } else {
          v = v>0.f?v:0.f;
          vC[rl*256 + colk] = (short)f2bf(v);
        }
      }
    }
    __syncthreads();
  }
}

// ---------------- K2: attention, one wave per (b,head); q read from / att written to A2 ----
__global__ __launch_bounds__(512,4) void k2_attn(const short* __restrict__ kC,
    const short* __restrict__ vC, const void* __restrict__ obsm, short* __restrict__ A2,
    const int* __restrict__ flagp, int chunkB){
  __shared__ __align__(16) short vT_s[8][2048];   // per-wave v^T [e=32][n=64]
  __shared__ __align__(16) short p_s[8][2048];    // per-wave p   [a=32][n=64]
  __shared__ unsigned char m_s[2048];             // obs_mask rows 0..31
  int t = threadIdx.x, bl = blockIdx.x;
  long b = (long)chunkB*2048 + bl;
  int lane = t&63, w = t>>6, lr = lane&15, ko = lane>>4;
  int mflag = *flagp;
  if (mflag){
    uchar4 mv = *(const uchar4*)((const unsigned char*)obsm + b*4096 + t*4);
    m_s[t*4]=mv.x; m_s[t*4+1]=mv.y; m_s[t*4+2]=mv.z; m_s[t*4+3]=mv.w;
  } else {
    int4 mv = *(const int4*)((const int*)obsm + b*4096 + t*4);
    m_s[t*4]  =(unsigned char)(mv.x!=0); m_s[t*4+1]=(unsigned char)(mv.y!=0);
    m_s[t*4+2]=(unsigned char)(mv.z!=0); m_s[t*4+3]=(unsigned char)(mv.w!=0);
  }
  const int h = w;
  const short* qh = A2 + ((long)b*32)*512 + h*32 + ko*8;   // q stored at stride 512
  bfrag a_q[2];
  #pragma unroll
  for (int mt=0; mt<2; mt++) a_q[mt] = *(const bfrag*)(qh + (long)(mt*16+lr)*512);
  const short* kh = kC + ((long)bl*64)*256 + h*32 + ko*8;
  bfrag b_k[4];
  #pragma unroll
  for (int nt=0; nt<4; nt++) b_k[nt] = *(const bfrag*)(kh + (nt*16+lr)*256);
  #pragma unroll
  for (int i=0;i<4;i++){
    int n = i*16 + (lane>>2); int e0 = (lane&3)*8;
    bfrag vv = *(const bfrag*)(vC + ((long)bl*64 + n)*256 + h*32 + e0);
    #pragma unroll
    for (int j=0;j<8;j++) vT_s[w][SWZ(e0+j, n, 64, 7)] = vv[j];
  }
  ffrag sc[2][4];
  #pragma unroll
  for (int mt=0; mt<2; mt++)
    #pragma unroll
    for (int nt=0; nt<4; nt++) sc[mt][nt] = MFMA(a_q[mt], b_k[nt], fzero());
  __syncthreads();   // m_s ready (vT/p are wave-private)
  const float scale = 0.17677669529663687f;   // 1/sqrt(32)
  float rsi[2][4];
  #pragma unroll
  for (int mt=0; mt<2; mt++){
    #pragma unroll
    for (int r=0; r<4; r++){
      int arow = mt*16 + ko*4 + r;
      float sv[4]; int mk[4];
      #pragma unroll
      for (int nt=0; nt<4; nt++){
        mk[nt] = m_s[arow*64 + nt*16 + lr];
        sv[nt] = sc[mt][nt][r] * scale;
      }
      float mx = -3.0e38f;
      #pragma unroll
      for (int nt=0; nt<4; nt++) if (!mk[nt]) mx = fmaxf(mx, sv[nt]);
      for (int d=1; d<16; d<<=1) mx = fmaxf(mx, __shfl_xor(mx, d));
      float sum = 0.f;
      #pragma unroll
      for (int nt=0; nt<4; nt++){
        float p = mk[nt] ? 0.f : __expf(sv[nt]-mx);
        sv[nt] = p; sum += p;
      }
      for (int d=1; d<16; d<<=1) sum += __shfl_xor(sum, d);
      rsi[mt][r] = sum > 0.f ? 1.f/sum : 0.f;   // all-masked row -> 0
      #pragma unroll
      for (int nt=0; nt<4; nt++)
        p_s[w][SWZ(arow, nt*16+lr, 64, 7)] = (short)f2bf(sv[nt]);
    }
  }
  ffrag o[2][2];
  #pragma unroll
  for (int mt=0;mt<2;mt++)
    #pragma unroll
    for (int nt=0;nt<2;nt++) o[mt][nt]=fzero();
  #pragma unroll
  for (int kk=0; kk<2; kk++){
    int kc = kk*32 + ko*8;
    bfrag pa0 = *(const bfrag*)(p_s[w]  + SWZ(lr,    kc, 64, 7));
    bfrag pa1 = *(const bfrag*)(p_s[w]  + SWZ(16+lr, kc, 64, 7));
    bfrag bv0 = *(const bfrag*)(vT_s[w] + SWZ(lr,    kc, 64, 7));
    bfrag bv1 = *(const bfrag*)(vT_s[w] + SWZ(16+lr, kc, 64, 7));
    o[0][0]=MFMA(pa0,bv0,o[0][0]); o[0][1]=MFMA(pa0,bv1,o[0][1]);
    o[1][0]=MFMA(pa1,bv0,o[1][0]); o[1][1]=MFMA(pa1,bv1,o[1][1]);
  }
  #pragma unroll
  for (int mt=0; mt<2; mt++)
    #pragma unroll
    for (int nt=0; nt<2; nt++)
      #pragma unroll
      for (int r=0; r<4; r++){
        int a = mt*16 + ko*4 + r;
        A2[((long)b*32 + a)*512 + h*32 + nt*16 + lr] = (short)f2bf(o[mt][nt][r]*rsi[mt][r]);
      }
}

// ---------------- K3: GRU via A2=[att|h0]; mt=1, jb-in-block, async-staged weights ----
// block = 128 rows (8 waves x 16). A-panel 16 bfrags (64 VGPR), read ONCE.
// Weights arrive via global_load_lds (linear fill of pre-swizzled source == SWZ layout).
__global__ __launch_bounds__(512) void k3_gru(const short* __restrict__ A2,
    const short* __restrict__ wihS, const short* __restrict__ whhS,
    const float* __restrict__ b_ih, const float* __restrict__ b_hh,
    const void* __restrict__ scen, float* __restrict__ hout, const int* __restrict__ flagp){
  __shared__ __align__(16) short w_s[2][24576];   // 2 x (3 slabs of 32x256) = 2 x 48 KB
  int t = threadIdx.x, bid = blockIdx.x;
  long R0 = (long)bid * 128;
  int mflag = *flagp;
  int lane = t&63, w = t>>6, lr = lane&15, ko = lane>>4;
  long rowbase = R0 + (long)w*16;   // wave owns 16 rows
  // async stage 48KB region (jb,part): linear copy, 6 gload16 per thread
  auto STAGE = [&](int jb, int part){
    const short* src = (part ? whhS : wihS) + (long)jb*24576;
    short* dst = w_s[part];
    #pragma unroll
    for (int i=0;i<6;i++)
      gload16(src + (long)(i*512 + t)*8, dst + (i*512 + (t & ~63))*8);
  };
  STAGE(0,0);   // flies under the A-panel loads
  // ---- load A-panel into registers (read once): 16 bfrags = 64 VGPR ----
  const short* Ab = A2 + (rowbase + lr)*512 + ko*8;
  bfrag A[16];
  #pragma unroll
  for (int ks=0; ks<16; ks++)
    A[ks] = *(const bfrag*)(Ab + ks*32);
  __syncthreads();
  for (int jb=0; jb<8; jb++){
    ffrag aR[2], aZ[2], aI[2], aN[2];   // [nt], 48 VGPR
    #pragma unroll
    for (int nt=0;nt<2;nt++){ aR[nt]=fzero(); aZ[nt]=fzero(); aI[nt]=fzero(); aN[nt]=fzero(); }
    // ---- part 0: wih x att (A ks 0..7) ----
    STAGE(jb,1);
    {
      const short* wc = w_s[0];
      #pragma unroll
      for (int ks=0; ks<8; ks++){
        int kc = ks*32 + ko*8;
        #pragma unroll
        for (int nt=0; nt<2; nt++){
          bfrag bR = *(const bfrag*)(wc + 0*8192 + SWZ(nt*16+lr, kc, 256, 7));
          aR[nt] = MFMA(A[ks], bR, aR[nt]);
          bfrag bZ = *(const bfrag*)(wc + 1*8192 + SWZ(nt*16+lr, kc, 256, 7));
          aZ[nt] = MFMA(A[ks], bZ, aZ[nt]);
          bfrag bX = *(const bfrag*)(wc + 2*8192 + SWZ(nt*16+lr, kc, 256, 7));
          aI[nt] = MFMA(A[ks], bX, aI[nt]);
        }
      }
    }
    __syncthreads();   // drains STAGE(jb,1); all part-0 reads done
    // ---- part 1: whh x h0 (A ks 8..15) ----
    if (jb < 7) STAGE(jb+1,0);
    {
      const short* wc = w_s[1];
      #pragma unroll
      for (int ks=0; ks<8; ks++){
        int kc = ks*32 + ko*8;
        #pragma unroll
        for (int nt=0; nt<2; nt++){
          bfrag bR = *(const bfrag*)(wc + 0*8192 + SWZ(nt*16+lr, kc, 256, 7));
          aR[nt] = MFMA(A[8+ks], bR, aR[nt]);
          bfrag bZ = *(const bfrag*)(wc + 1*8192 + SWZ(nt*16+lr, kc, 256, 7));
          aZ[nt] = MFMA(A[8+ks], bZ, aZ[nt]);
          bfrag bX = *(const bfrag*)(wc + 2*8192 + SWZ(nt*16+lr, kc, 256, 7));
          aN[nt] = MFMA(A[8+ks], bX, aN[nt]);
        }
      }
    }
    // ---- epilogue for jb's 32 cols ----
    #pragma unroll
    for (int nt=0; nt<2; nt++){
      int j = jb*32 + nt*16 + lr;
      float bir = b_ih[j],     bhr = b_hh[j];
      float biz = b_ih[256+j], bhz = b_hh[256+j];
      float bin = b_ih[512+j], bhn = b_hh[512+j];
      #pragma unroll
      for (int rr=0; rr<4; rr++){
        long row = rowbase + ko*4 + rr;
        float rg = 1.f/(1.f + __expf(-(aR[nt][rr] + bir + bhr)));
        float zg = 1.f/(1.f + __expf(-(aZ[nt][rr] + biz + bhz)));
        float ag = aI[nt][rr] + bin + rg*(aN[nt][rr] + bhn);
        float ng = 2.f/(1.f + __expf(-2.f*ag)) - 1.f;   // tanh
        float h0v = bf2f(A2[row*512 + 256 + j]);
        float hv = (1.f - zg)*ng + zg*h0v;
        if (getmask(scen, row, mflag)) hv = 0.f;
        hout[row*256 + j] = hv;
      }
    }
    __syncthreads();   // part-1 reads done before next jb overwrites w_s[1]
  }
}

// ---------------- K4: q_out = h @ out_w^T + out_b (masked) ----------------
__global__ __launch_bounds__(512) void k4_out(const float* __restrict__ hout,
    const short* __restrict__ ow, const float* __restrict__ out_b,
    const void* __restrict__ scen, float* __restrict__ qout, const int* __restrict__ flagp){
  __shared__ __align__(16) short ow_s[32*256];
  int t = threadIdx.x; long R0 = (long)blockIdx.x * 256;
  int mflag = *flagp;
  for (int i=0;i<2;i++){
    int c = t + i*512; int row = c >> 5; int cc = (c & 31)*8;
    *(bfrag*)(ow_s + SWZ(row, cc, 256, 7)) = *(const bfrag*)(ow + row*256 + cc);
  }
  __syncthreads();
  int lane = t&63, w = t>>6, lr = lane&15, ko = lane>>4;
  ffrag acc[2][2];
  #pragma unroll
  for (int a=0;a<2;a++) for (int bq=0;bq<2;bq++) acc[a][bq]=fzero();
  for (int ks=0; ks<8; ks++){
    int kc = ks*32 + ko*8;
    #pragma unroll
    for (int mi=0; mi<2; mi++){
      long row = R0 + (w*2+mi)*16 + lr;
      const float* hp = hout + row*256 + kc;
      float4 f0 = *(const float4*)hp; float4 f1 = *(const float4*)(hp+4);
      bfrag a;
      a[0]=(short)f2bf(f0.x); a[1]=(short)f2bf(f0.y); a[2]=(short)f2bf(f0.z); a[3]=(short)f2bf(f0.w);
      a[4]=(short)f2bf(f1.x); a[5]=(short)f2bf(f1.y); a[6]=(short)f2bf(f1.z); a[7]=(short)f2bf(f1.w);
      #pragma unroll
      for (int nt=0; nt<2; nt++){
        bfrag bb = *(const bfrag*)(ow_s + SWZ(nt*16+lr, kc, 256, 7));
        acc[mi][nt] = MFMA(a, bb, acc[mi][nt]);
      }
    }
  }
  #pragma unroll
  for (int mi=0;mi<2;mi++)
    #pragma unroll
    for (int nt=0;nt<2;nt++){
      int col = nt*16 + lr;
      float ob = out_b[col];
      #pragma unroll
      for (int r=0;r<4;r++){
        long row = R0 + (w*2+mi)*16 + ko*4 + r;
        float qv = acc[mi][nt][r] + ob;
        if (getmask(scen, row, mflag)) qv = 0.f;
        qout[row*32 + col] = qv;
      }
    }
}

extern "C" void kernel_launch(void* const* d_in, const int* in_sizes, int n_in,
                              void* d_out, int out_size, void* d_ws, size_t ws_size,
                              hipStream_t stream){
  const float* inputs = (const float*)d_in[0];
  const float* hidden = (const float*)d_in[1];
  const float* fc1_w  = (const float*)d_in[2];
  const float* fc1_b  = (const float*)d_in[3];
  const float* q_w    = (const float*)d_in[4];
  const float* q_b    = (const float*)d_in[5];
  const float* k_w    = (const float*)d_in[6];
  const float* k_b    = (const float*)d_in[7];
  const float* v_w    = (const float*)d_in[8];
  const float* v_b    = (const float*)d_in[9];
  const float* w_ih   = (const float*)d_in[10];
  const float* w_hh   = (const float*)d_in[11];
  const float* b_ih   = (const float*)d_in[12];
  const float* b_hh   = (const float*)d_in[13];
  const float* out_w  = (const float*)d_in[14];
  const float* out_b  = (const float*)d_in[15];
  const void* obsm    = d_in[16];
  const void* scen    = d_in[17];
  (void)in_sizes; (void)n_in; (void)out_size;
  if ((long)ws_size < WS_NEED_BYTES) return;
  short* ws = (short*)d_ws;
  const int* flagp = (const int*)(ws + OFF_FLAG);
  float* qout = (float*)d_out;
  float* hout = qout + 4194304;
  // per-chunk k/v scratch in the dead hout region (2048 batches/chunk):
  short* kCs = (short*)hout;             // 2048*64*256 shorts = 67 MB
  short* vCs = kCs + 33554432L;          // 67 MB
  short* A2  = ws + OFF_A2;

  hipLaunchKernelGGL(k0_prep, dim3(2048), dim3(256), 0, stream,
      fc1_w, q_w, k_w, v_w, w_ih, w_hh, out_w, hidden, obsm, ws);
  for (int c=0; c<2; c++){
    hipLaunchKernelGGL(k1_fqkv, dim3(1024), dim3(512), 0, stream,
        inputs, ws + OFF_FC1, fc1_b, ws + OFF_QW, ws + OFF_KW, ws + OFF_VW,
        q_b, k_b, v_b, A2, kCs, vCs, c);
    hipLaunchKernelGGL(k2_attn, dim3(2048), dim3(512), 0, stream,
        kCs, vCs, obsm, A2, flagp, c);
  }
  hipLaunchKernelGGL(k3_gru, dim3(1024), dim3(512), 0, stream,
      A2, ws + OFF_WIH, ws + OFF_WHH, b_ih, b_hh, scen, hout, flagp);
  hipLaunchKernelGGL(k4_out, dim3(512), dim3(512), 0, stream,
      hout, ws + OFF_OW, out_b, scen, qout, flagp);
}

// Round 11
// 612.530 us; speedup vs baseline: 1.1338x; 1.0004x over previous
//
#include <hip/hip_runtime.h>

// ATTNRNNAgent: B=4096, N=64, E=128, A=32, nh=8, e=32, HID=256, ATT=256, N_ACT=32
// K0 -> 2x( k1_fqkv, k2_attn ) -> k3_gru -> k4_out
// k3: mt=1, jb-in-block, global_load_lds staging of PRE-SWIZZLED weights (rule #21).
//   R11 change: ping-pong at 2-slab granularity (2x32KB = 64KB LDS, was 96KB) ->
//   2 blocks/CU -> 4 waves/SIMD. Same read/MFMA counts; hides the b128 conflict
//   stalls that held R10 at 236us (Occupancy 22%, MfmaUtil 18%).
//   Weights repacked by k0 as W6[jb][6 gates][32][256] (wih.r,z,n,whh.r,z,n).
// q is stored in-place in A2's att columns (k2 reads q, overwrites with att).

using bfrag = __attribute__((ext_vector_type(8))) short;   // 8 bf16
using ffrag = __attribute__((ext_vector_type(4))) float;   // 4 f32 acc

#define MFMA(a,b,c) __builtin_amdgcn_mfma_f32_16x16x32_bf16((a),(b),(c),0,0,0)
// XOR swizzle for row-major bf16 LDS tiles (16B granular)
#define SWZ(row,col,S,xm) ((row)*(S) + ((((col)&~7) ^ (((row)&(xm))<<3)) | ((col)&7)))

// ws layout (in shorts). A2 first (131072 x 512), then bf16 weights, then flag.
#define OFF_A2   0L
#define OFF_FC1  67108864L
#define OFF_QW   67141632L
#define OFF_KW   67207168L
#define OFF_VW   67272704L
#define OFF_W6   67338240L   // k3 W6: [jb][6 gates][32][256], pre-swizzled (393216 shorts)
#define OFF_OW   67731456L
#define OFF_FLAG 67739648L
#define WS_NEED_BYTES 135479552L

__device__ inline unsigned short f2bf(float x){
  union { float f; unsigned u; } v; v.f = x;
  unsigned r = v.u + 0x7fffu + ((v.u >> 16) & 1u);   // RNE
  return (unsigned short)(r >> 16);
}
__device__ inline float bf2f(short b){
  union { unsigned u; float f; } v; v.u = ((unsigned)(unsigned short)b) << 16;
  return v.f;
}
__device__ inline bool getmask(const void* p, long i, int byteflag){
  return byteflag ? (((const unsigned char*)p)[i] != 0)
                  : (((const int*)p)[i] != 0);
}
__device__ inline ffrag fzero(){ ffrag z; z[0]=0.f; z[1]=0.f; z[2]=0.f; z[3]=0.f; return z; }
// async global->LDS, 16B per lane; lds ptr must be wave-uniform (HW adds lane*16)
__device__ inline void gload16(const short* g, short* l){
  __builtin_amdgcn_global_load_lds((const __attribute__((address_space(1))) void*)g,
                                   (__attribute__((address_space(3))) void*)l, 16, 0, 0);
}

// ---------------- K0: weights -> bf16 (k3 W6 pre-swizzled), A2 h0-half, mask dtype ----
__global__ void k0_prep(const float* __restrict__ fc1, const float* __restrict__ qw,
    const float* __restrict__ kw, const float* __restrict__ vw, const float* __restrict__ wih,
    const float* __restrict__ whh, const float* __restrict__ ow, const float* __restrict__ h0,
    const void* __restrict__ obsm, short* __restrict__ ws){
  long tid = (long)blockIdx.x*blockDim.x + threadIdx.x;
  long n = (long)gridDim.x*blockDim.x;
  if (tid == 0){
    const int* mi = (const int*)obsm;
    int f = 0;
    for (int i=0;i<256;i++){ if ((unsigned)mi[i] > 1u){ f = 1; break; } }
    ((int*)(ws + OFF_FLAG))[0] = f;
  }
  for (long i=tid; i<32768; i+=n) ws[OFF_FC1+i] = (short)f2bf(fc1[i]);
  for (long i=tid; i<65536; i+=n){
    ws[OFF_QW+i] = (short)f2bf(qw[i]);
    ws[OFF_KW+i] = (short)f2bf(kw[i]);
    ws[OFF_VW+i] = (short)f2bf(vw[i]);
  }
  // k3 W6: [jb][g][row32][256], g = {wih.r, wih.z, wih.n, whh.r, whh.z, whh.n};
  // columns pre-swizzled so a LINEAR global_load_lds fill == SWZ layout of the reads.
  for (long i=tid; i<196608; i+=n){
    int gate = (int)(i >> 16);
    int grow = (int)((i >> 8) & 255);
    int c = (int)(i & 255);
    int jb = grow >> 5, row = grow & 31;
    int cs = c ^ ((row&7)<<3);
    ws[OFF_W6 + ((long)((jb*6 + gate)*32 + row))*256 + cs]     = (short)f2bf(wih[i]);
    ws[OFF_W6 + ((long)((jb*6 + 3 + gate)*32 + row))*256 + cs] = (short)f2bf(whh[i]);
  }
  for (long i=tid; i<8192; i+=n) ws[OFF_OW+i] = (short)f2bf(ow[i]);
  // A2 h0 half (2 floats -> 1 packed uint): A2[row*512+256+2j..+1] = bf16(h0[row*256+2j..])
  const float2* h2 = (const float2*)h0;
  unsigned* a2u = (unsigned*)(ws + OFF_A2);
  for (long i=tid; i<16777216L; i+=n){
    long row = i >> 7; int j = (int)(i & 127);
    float2 v = h2[i];
    unsigned pk = (unsigned)f2bf(v.x) | ((unsigned)f2bf(v.y) << 16);
    a2u[row*256 + 128 + j] = pk;
  }
}

// ---------------- K1: fused fc1 + QKV projection (per 131072-row chunk) ----------------
__global__ __launch_bounds__(512) void k1_fqkv(const float* __restrict__ inp,
    const short* __restrict__ fc1B, const float* __restrict__ fc1_b,
    const short* __restrict__ wq, const short* __restrict__ wk, const short* __restrict__ wv,
    const float* __restrict__ qb, const float* __restrict__ kb, const float* __restrict__ vb,
    short* __restrict__ A2, short* __restrict__ kC, short* __restrict__ vC, int chunkB){
  __shared__ __align__(16) short smem[65536];   // 128 KB
  short* a_s  = smem;            // phase1 A: 128x128 (32 KB)
  short* fw_s = smem + 16384;    // phase1 W: 256x128 (64 KB)
  short* x_s  = smem;            // phase2 X: 128x256 (64 KB)
  int t = threadIdx.x;
  long R0 = (long)blockIdx.x * 128;            // chunk-local row base
  long grow0 = (long)chunkB*131072 + R0;       // global input row base
  int lane = t&63, w = t>>6, lr = lane&15, ko = lane>>4;
  for (int i=0;i<4;i++){
    int c = t + i*512; int row = c>>4; int cc = (c&15)*8;
    const float* src = inp + (grow0 + row)*128 + cc;
    float4 f0 = *(const float4*)src; float4 f1 = *(const float4*)(src+4);
    bfrag v8;
    v8[0]=(short)f2bf(f0.x); v8[1]=(short)f2bf(f0.y); v8[2]=(short)f2bf(f0.z); v8[3]=(short)f2bf(f0.w);
    v8[4]=(short)f2bf(f1.x); v8[5]=(short)f2bf(f1.y); v8[6]=(short)f2bf(f1.z); v8[7]=(short)f2bf(f1.w);
    *(bfrag*)(a_s + SWZ(row, cc, 128, 7)) = v8;
  }
  for (int i=0;i<8;i++){
    int c = t + i*512; int row = c>>4; int cc = (c&15)*8;
    *(bfrag*)(fw_s + SWZ(row, cc, 128, 7)) = *(const bfrag*)(fc1B + row*128 + cc);
  }
  __syncthreads();
  ffrag acc1[16];
  #pragma unroll
  for (int i=0;i<16;i++) acc1[i]=fzero();
  for (int ks=0; ks<4; ks++){
    int kc = ks*32 + ko*8;
    bfrag a = *(const bfrag*)(a_s + SWZ(w*16+lr, kc, 128, 7));
    #pragma unroll
    for (int nt=0; nt<16; nt++){
      bfrag bb = *(const bfrag*)(fw_s + SWZ(nt*16+lr, kc, 128, 7));
      acc1[nt] = MFMA(a, bb, acc1[nt]);
    }
  }
  __syncthreads();   // all phase1 LDS reads complete -> reuse smem
  #pragma unroll
  for (int nt=0; nt<16; nt++){
    float bias = fc1_b[nt*16+lr];
    #pragma unroll
    for (int r=0;r<4;r++){
      int row = w*16 + ko*4 + r;
      float v = acc1[nt][r] + bias; v = v>0.f?v:0.f;
      x_s[SWZ(row, nt*16+lr, 256, 7)] = (short)f2bf(v);
    }
  }
  bfrag a_r[8];
  #pragma unroll
  for (int ks=0; ks<8; ks++)
    a_r[ks] = *(const bfrag*)(x_s + SWZ(w*16+lr, ks*32+ko*8, 256, 7));
  auto STAGE2 = [&](int s){
    int kind = s>>2; int rb = (s&3)*64;
    const short* wsrc = (kind==0?wq:(kind==1?wk:wv)) + (long)rb*256;
    short* dst = smem + 32768 + (s&1)*16384;
    #pragma unroll
    for (int i=0;i<4;i++){
      int c = t + i*512; int row = c>>5; int cc = (c&31)*8;
      *(bfrag*)(dst + SWZ(row, cc, 256, 7)) = *(const bfrag*)(wsrc + (long)row*256 + cc);
    }
  };
  STAGE2(0);
  __syncthreads();
  for (int s=0; s<12; s++){
    if (s < 11) STAGE2(s+1);
    const short* wcur = smem + 32768 + (s&1)*16384;
    ffrag acc2[4];
    #pragma unroll
    for (int i=0;i<4;i++) acc2[i]=fzero();
    #pragma unroll
    for (int ks=0; ks<8; ks++){
      int kc = ks*32 + ko*8;
      #pragma unroll
      for (int nt=0; nt<4; nt++){
        bfrag bb = *(const bfrag*)(wcur + SWZ(nt*16+lr, kc, 256, 7));
        acc2[nt] = MFMA(a_r[ks], bb, acc2[nt]);
      }
    }
    int kind = s>>2; int rb = (s&3)*64;
    const float* bsrc = (kind==0?qb:(kind==1?kb:vb));
    #pragma unroll
    for (int nt=0; nt<4; nt++){
      int colk = rb + nt*16 + lr;
      float bias = bsrc[colk];
      #pragma unroll
      for (int r=0;r<4;r++){
        int row = w*16 + ko*4 + r;
        long rl = R0 + row;
        float v = acc2[nt][r] + bias;
        if (kind==0){
          if ((row&32)==0){                       // q: only agent rows n<32
            long grow = grow0 + row;
            long qrow = ((grow>>6)<<5) + (grow&31);
            A2[qrow*512 + colk] = (short)f2bf(v);  // q in-place in A2 att cols
          }
        } else if (kind==1){
          kC[rl*256 + colk] = (short)f2bf(v);
        } else {
          v = v>0.f?v:0.f;
          vC[rl*256 + colk] = (short)f2bf(v);
        }
      }
    }
    __syncthreads();
  }
}

// ---------------- K2: attention, one wave per (b,head); q read from / att written to A2 ----
__global__ __launch_bounds__(512,4) void k2_attn(const short* __restrict__ kC,
    const short* __restrict__ vC, const void* __restrict__ obsm, short* __restrict__ A2,
    const int* __restrict__ flagp, int chunkB){
  __shared__ __align__(16) short vT_s[8][2048];   // per-wave v^T [e=32][n=64]
  __shared__ __align__(16) short p_s[8][2048];    // per-wave p   [a=32][n=64]
  __shared__ unsigned char m_s[2048];             // obs_mask rows 0..31
  int t = threadIdx.x, bl = blockIdx.x;
  long b = (long)chunkB*2048 + bl;
  int lane = t&63, w = t>>6, lr = lane&15, ko = lane>>4;
  int mflag = *flagp;
  if (mflag){
    uchar4 mv = *(const uchar4*)((const unsigned char*)obsm + b*4096 + t*4);
    m_s[t*4]=mv.x; m_s[t*4+1]=mv.y; m_s[t*4+2]=mv.z; m_s[t*4+3]=mv.w;
  } else {
    int4 mv = *(const int4*)((const int*)obsm + b*4096 + t*4);
    m_s[t*4]  =(unsigned char)(mv.x!=0); m_s[t*4+1]=(unsigned char)(mv.y!=0);
    m_s[t*4+2]=(unsigned char)(mv.z!=0); m_s[t*4+3]=(unsigned char)(mv.w!=0);
  }
  const int h = w;
  const short* qh = A2 + ((long)b*32)*512 + h*32 + ko*8;   // q stored at stride 512
  bfrag a_q[2];
  #pragma unroll
  for (int mt=0; mt<2; mt++) a_q[mt] = *(const bfrag*)(qh + (long)(mt*16+lr)*512);
  const short* kh = kC + ((long)bl*64)*256 + h*32 + ko*8;
  bfrag b_k[4];
  #pragma unroll
  for (int nt=0; nt<4; nt++) b_k[nt] = *(const bfrag*)(kh + (nt*16+lr)*256);
  #pragma unroll
  for (int i=0;i<4;i++){
    int n = i*16 + (lane>>2); int e0 = (lane&3)*8;
    bfrag vv = *(const bfrag*)(vC + ((long)bl*64 + n)*256 + h*32 + e0);
    #pragma unroll
    for (int j=0;j<8;j++) vT_s[w][SWZ(e0+j, n, 64, 7)] = vv[j];
  }
  ffrag sc[2][4];
  #pragma unroll
  for (int mt=0; mt<2; mt++)
    #pragma unroll
    for (int nt=0; nt<4; nt++) sc[mt][nt] = MFMA(a_q[mt], b_k[nt], fzero());
  __syncthreads();   // m_s ready (vT/p are wave-private)
  const float scale = 0.17677669529663687f;   // 1/sqrt(32)
  float rsi[2][4];
  #pragma unroll
  for (int mt=0; mt<2; mt++){
    #pragma unroll
    for (int r=0; r<4; r++){
      int arow = mt*16 + ko*4 + r;
      float sv[4]; int mk[4];
      #pragma unroll
      for (int nt=0; nt<4; nt++){
        mk[nt] = m_s[arow*64 + nt*16 + lr];
        sv[nt] = sc[mt][nt][r] * scale;
      }
      float mx = -3.0e38f;
      #pragma unroll
      for (int nt=0; nt<4; nt++) if (!mk[nt]) mx = fmaxf(mx, sv[nt]);
      for (int d=1; d<16; d<<=1) mx = fmaxf(mx, __shfl_xor(mx, d));
      float sum = 0.f;
      #pragma unroll
      for (int nt=0; nt<4; nt++){
        float p = mk[nt] ? 0.f : __expf(sv[nt]-mx);
        sv[nt] = p; sum += p;
      }
      for (int d=1; d<16; d<<=1) sum += __shfl_xor(sum, d);
      rsi[mt][r] = sum > 0.f ? 1.f/sum : 0.f;   // all-masked row -> 0
      #pragma unroll
      for (int nt=0; nt<4; nt++)
        p_s[w][SWZ(arow, nt*16+lr, 64, 7)] = (short)f2bf(sv[nt]);
    }
  }
  ffrag o[2][2];
  #pragma unroll
  for (int mt=0;mt<2;mt++)
    #pragma unroll
    for (int nt=0;nt<2;nt++) o[mt][nt]=fzero();
  #pragma unroll
  for (int kk=0; kk<2; kk++){
    int kc = kk*32 + ko*8;
    bfrag pa0 = *(const bfrag*)(p_s[w]  + SWZ(lr,    kc, 64, 7));
    bfrag pa1 = *(const bfrag*)(p_s[w]  + SWZ(16+lr, kc, 64, 7));
    bfrag bv0 = *(const bfrag*)(vT_s[w] + SWZ(lr,    kc, 64, 7));
    bfrag bv1 = *(const bfrag*)(vT_s[w] + SWZ(16+lr, kc, 64, 7));
    o[0][0]=MFMA(pa0,bv0,o[0][0]); o[0][1]=MFMA(pa0,bv1,o[0][1]);
    o[1][0]=MFMA(pa1,bv0,o[1][0]); o[1][1]=MFMA(pa1,bv1,o[1][1]);
  }
  #pragma unroll
  for (int mt=0; mt<2; mt++)
    #pragma unroll
    for (int nt=0; nt<2; nt++)
      #pragma unroll
      for (int r=0; r<4; r++){
        int a = mt*16 + ko*4 + r;
        A2[((long)b*32 + a)*512 + h*32 + nt*16 + lr] = (short)f2bf(o[mt][nt][r]*rsi[mt][r]);
      }
}

// ---------------- K3: GRU via A2=[att|h0]; mt=1, 2-slab ping-pong (64KB), async staging ----
// block = 128 rows (8 waves x 16). A-panel 16 bfrags (64 VGPR), read ONCE.
// 24 phases (8 jb x 3): p0={wih.r,wih.z}, p1={wih.n,whh.r}, p2={whh.z,whh.n}.
// 64KB LDS -> 2 blocks/CU -> 4 waves/SIMD (R10 was 96KB -> 1 block -> 2 waves/SIMD).
__global__ __launch_bounds__(512) void k3_gru(const short* __restrict__ A2,
    const short* __restrict__ w6, const float* __restrict__ b_ih, const float* __restrict__ b_hh,
    const void* __restrict__ scen, float* __restrict__ hout, const int* __restrict__ flagp){
  __shared__ __align__(16) short w_s[2][16384];   // 2 x (2 slabs of 32x256) = 2 x 32 KB
  int t = threadIdx.x, bid = blockIdx.x;
  long R0 = (long)bid * 128;
  int mflag = *flagp;
  int lane = t&63, w = t>>6, lr = lane&15, ko = lane>>4;
  long rowbase = R0 + (long)w*16;   // wave owns 16 rows
  // async stage phase ph (32KB linear from pre-swizzled W6), 4 gload16 per thread
  auto STAGE = [&](int ph){
    const short* src = w6 + (long)ph*16384;
    short* dst = w_s[ph&1];
    #pragma unroll
    for (int i=0;i<4;i++)
      gload16(src + (long)(i*512 + t)*8, dst + (i*512 + (t & ~63))*8);
  };
  STAGE(0);   // flies under the A-panel loads
  // ---- load A-panel into registers (read once): 16 bfrags = 64 VGPR ----
  const short* Ab = A2 + (rowbase + lr)*512 + ko*8;
  bfrag A[16];
  #pragma unroll
  for (int ks=0; ks<16; ks++)
    A[ks] = *(const bfrag*)(Ab + ks*32);
  __syncthreads();
  for (int jb=0; jb<8; jb++){
    ffrag aR[2], aZ[2], aI[2], aN[2];   // [nt]
    #pragma unroll
    for (int nt=0;nt<2;nt++){ aR[nt]=fzero(); aZ[nt]=fzero(); aI[nt]=fzero(); aN[nt]=fzero(); }
    #pragma unroll
    for (int p=0; p<3; p++){
      int ph = jb*3 + p;
      if (ph < 23) STAGE(ph+1);
      const short* wc = w_s[ph&1];
      #pragma unroll
      for (int ks=0; ks<8; ks++){
        int kc = ks*32 + ko*8;
        #pragma unroll
        for (int nt=0; nt<2; nt++){
          bfrag b0 = *(const bfrag*)(wc + SWZ(nt*16+lr, kc, 256, 7));
          bfrag b1 = *(const bfrag*)(wc + 8192 + SWZ(nt*16+lr, kc, 256, 7));
          if (p == 0){
            aR[nt] = MFMA(A[ks], b0, aR[nt]);       // wih.r x att
            aZ[nt] = MFMA(A[ks], b1, aZ[nt]);       // wih.z x att
          } else if (p == 1){
            aI[nt] = MFMA(A[ks], b0, aI[nt]);       // wih.n x att
            aR[nt] = MFMA(A[8+ks], b1, aR[nt]);     // whh.r x h0
          } else {
            aZ[nt] = MFMA(A[8+ks], b0, aZ[nt]);     // whh.z x h0
            aN[nt] = MFMA(A[8+ks], b1, aN[nt]);     // whh.n x h0
          }
        }
      }
      if (p == 2){   // epilogue for jb's 32 cols (registers + global only)
        #pragma unroll
        for (int nt=0; nt<2; nt++){
          int j = jb*32 + nt*16 + lr;
          float bir = b_ih[j],     bhr = b_hh[j];
          float biz = b_ih[256+j], bhz = b_hh[256+j];
          float bin = b_ih[512+j], bhn = b_hh[512+j];
          #pragma unroll
          for (int rr=0; rr<4; rr++){
            long row = rowbase + ko*4 + rr;
            float rg = 1.f/(1.f + __expf(-(aR[nt][rr] + bir + bhr)));
            float zg = 1.f/(1.f + __expf(-(aZ[nt][rr] + biz + bhz)));
            float ag = aI[nt][rr] + bin + rg*(aN[nt][rr] + bhn);
            float ng = 2.f/(1.f + __expf(-2.f*ag)) - 1.f;   // tanh
            float h0v = bf2f(A2[row*512 + 256 + j]);
            float hv = (1.f - zg)*ng + zg*h0v;
            if (getmask(scen, row, mflag)) hv = 0.f;
            hout[row*256 + j] = hv;
          }
        }
      }
      __syncthreads();   // drains this phase's STAGE; all reads of wc done
    }
  }
}

// ---------------- K4: q_out = h @ out_w^T + out_b (masked) ----------------
__global__ __launch_bounds__(512) void k4_out(const float* __restrict__ hout,
    const short* __restrict__ ow, const float* __restrict__ out_b,
    const void* __restrict__ scen, float* __restrict__ qout, const int* __restrict__ flagp){
  __shared__ __align__(16) short ow_s[32*256];
  int t = threadIdx.x; long R0 = (long)blockIdx.x * 256;
  int mflag = *flagp;
  for (int i=0;i<2;i++){
    int c = t + i*512; int row = c >> 5; int cc = (c & 31)*8;
    *(bfrag*)(ow_s + SWZ(row, cc, 256, 7)) = *(const bfrag*)(ow + row*256 + cc);
  }
  __syncthreads();
  int lane = t&63, w = t>>6, lr = lane&15, ko = lane>>4;
  ffrag acc[2][2];
  #pragma unroll
  for (int a=0;a<2;a++) for (int bq=0;bq<2;bq++) acc[a][bq]=fzero();
  for (int ks=0; ks<8; ks++){
    int kc = ks*32 + ko*8;
    #pragma unroll
    for (int mi=0; mi<2; mi++){
      long row = R0 + (w*2+mi)*16 + lr;
      const float* hp = hout + row*256 + kc;
      float4 f0 = *(const float4*)hp; float4 f1 = *(const float4*)(hp+4);
      bfrag a;
      a[0]=(short)f2bf(f0.x); a[1]=(short)f2bf(f0.y); a[2]=(short)f2bf(f0.z); a[3]=(short)f2bf(f0.w);
      a[4]=(short)f2bf(f1.x); a[5]=(short)f2bf(f1.y); a[6]=(short)f2bf(f1.z); a[7]=(short)f2bf(f1.w);
      #pragma unroll
      for (int nt=0; nt<2; nt++){
        bfrag bb = *(const bfrag*)(ow_s + SWZ(nt*16+lr, kc, 256, 7));
        acc[mi][nt] = MFMA(a, bb, acc[mi][nt]);
      }
    }
  }
  #pragma unroll
  for (int mi=0;mi<2;mi++)
    #pragma unroll
    for (int nt=0;nt<2;nt++){
      int col = nt*16 + lr;
      float ob = out_b[col];
      #pragma unroll
      for (int r=0;r<4;r++){
        long row = R0 + (w*2+mi)*16 + ko*4 + r;
        float qv = acc[mi][nt][r] + ob;
        if (getmask(scen, row, mflag)) qv = 0.f;
        qout[row*32 + col] = qv;
      }
    }
}

extern "C" void kernel_launch(void* const* d_in, const int* in_sizes, int n_in,
                              void* d_out, int out_size, void* d_ws, size_t ws_size,
                              hipStream_t stream){
  const float* inputs = (const float*)d_in[0];
  const float* hidden = (const float*)d_in[1];
  const float* fc1_w  = (const float*)d_in[2];
  const float* fc1_b  = (const float*)d_in[3];
  const float* q_w    = (const float*)d_in[4];
  const float* q_b    = (const float*)d_in[5];
  const float* k_w    = (const float*)d_in[6];
  const float* k_b    = (const float*)d_in[7];
  const float* v_w    = (const float*)d_in[8];
  const float* v_b    = (const float*)d_in[9];
  const float* w_ih   = (const float*)d_in[10];
  const float* w_hh   = (const float*)d_in[11];
  const float* b_ih   = (const float*)d_in[12];
  const float* b_hh   = (const float*)d_in[13];
  const float* out_w  = (const float*)d_in[14];
  const float* out_b  = (const float*)d_in[15];
  const void* obsm    = d_in[16];
  const void* scen    = d_in[17];
  (void)in_sizes; (void)n_in; (void)out_size;
  if ((long)ws_size < WS_NEED_BYTES) return;
  short* ws = (short*)d_ws;
  const int* flagp = (const int*)(ws + OFF_FLAG);
  float* qout = (float*)d_out;
  float* hout = qout + 4194304;
  // per-chunk k/v scratch in the dead hout region (2048 batches/chunk):
  short* kCs = (short*)hout;             // 2048*64*256 shorts = 67 MB
  short* vCs = kCs + 33554432L;          // 67 MB
  short* A2  = ws + OFF_A2;

  hipLaunchKernelGGL(k0_prep, dim3(2048), dim3(256), 0, stream,
      fc1_w, q_w, k_w, v_w, w_ih, w_hh, out_w, hidden, obsm, ws);
  for (int c=0; c<2; c++){
    hipLaunchKernelGGL(k1_fqkv, dim3(1024), dim3(512), 0, stream,
        inputs, ws + OFF_FC1, fc1_b, ws + OFF_QW, ws + OFF_KW, ws + OFF_VW,
        q_b, k_b, v_b, A2, kCs, vCs, c);
    hipLaunchKernelGGL(k2_attn, dim3(2048), dim3(512), 0, stream,
        kCs, vCs, obsm, A2, flagp, c);
  }
  hipLaunchKernelGGL(k3_gru, dim3(1024), dim3(512), 0, stream,
      A2, ws + OFF_W6, b_ih, b_hh, scen, hout, flagp);
  hipLaunchKernelGGL(k4_out, dim3(512), dim3(512), 0, stream,
      hout, ws + OFF_OW, out_b, scen, qout, flagp);
}